// Round 11
// baseline (428.442 us; speedup 1.0000x reference)
//
#include <hip/hip_runtime.h>
#include <hip/hip_bf16.h>

// Problem constants
#define B_    8
#define C_    96
#define N_    3136      // 56*56
#define COUT_ 192
#define NTOK_ 25088     // B_*N_
#define BN_EPS 1e-5f

#define QROW 104        // K LDS token-row stride in bf16 (96+8), 16B-multiple rows
#define VROW 72         // VT row stride in bf16 (64+8), 16B-multiple
#define CROW 200        // conv cat LDS token-row stride in bf16 (192+8), 16B-multiple
#define BNC  (B_ * N_ * C_)
#define NSPLIT 4

typedef __hip_bfloat16 bf16;
typedef unsigned short u16;
typedef unsigned int u32;
typedef __attribute__((ext_vector_type(8))) short short8;    // 8 bf16 = 16B (MFMA A/B frag)
typedef __attribute__((ext_vector_type(16))) float f32x16;   // 32x32 MFMA C/D frag

__device__ __forceinline__ u16 f2bf(float f) {
    union { __hip_bfloat16 h; u16 u; } cv;
    cv.h = __float2bfloat16(f);
    return cv.u;
}
__device__ __forceinline__ float bf2f(u16 v) {
    union { u16 u; __hip_bfloat16 h; } cv;
    cv.u = v;
    return __bfloat162float(cv.h);
}
__device__ __forceinline__ u32 packbf2(float lo, float hi) {
    return ((u32)f2bf(hi) << 16) | (u32)f2bf(lo);
}

// ---------------------------------------------------------------------------
// K1: x [B][C][N] fp32 -> xt_hi/xt_lo [B][N][C] bf16 (token-major, hi/lo split)
//                         xc_hi [B][C][N] bf16 (channel-major, for V^T staging)
// Fused: per-token squared-norm partial sums (32 channels per block) -> norm2.
__global__ __launch_bounds__(256) void transpose_split(const float* __restrict__ x,
                                                       u16* __restrict__ xt_hi,
                                                       u16* __restrict__ xt_lo,
                                                       u16* __restrict__ xc_hi,
                                                       float* __restrict__ norm2) {
    __shared__ float tile[32][33];
    __shared__ float nrm[32];
    const int nb = blockIdx.x * 32;
    const int cb = blockIdx.y * 32;
    const int b  = blockIdx.z;
    const int tid = threadIdx.x;
    const int tx = tid & 31;
    const int ty = tid >> 5;
    if (tid < 32) nrm[tid] = 0.0f;
    float psum = 0.0f;
#pragma unroll
    for (int r = 0; r < 32; r += 8) {
        size_t idx = ((size_t)b * C_ + cb + ty + r) * N_ + nb + tx;
        float v = x[idx];
        tile[ty + r][tx] = v;
        xc_hi[idx] = f2bf(v);
        psum = fmaf(v, v, psum);
    }
    __syncthreads();               // tile visible; nrm init done
    atomicAdd(&nrm[tx], psum);     // LDS atomic, 8 adders per slot
#pragma unroll
    for (int r = 0; r < 32; r += 8) {
        float v = tile[tx][ty + r];
        u16 h = f2bf(v);
        size_t o = ((size_t)b * N_ + nb + ty + r) * C_ + cb + tx;
        xt_hi[o] = h;
        xt_lo[o] = f2bf(v - bf2f(h));
    }
    __syncthreads();               // nrm complete
    if (tid < 32)
        atomicAdd(&norm2[(size_t)b * N_ + nb + tid], nrm[tid]);
}

// K1b: conv_w [O][2C] fp32 -> whi/wlo bf16 (same [o][c] layout, hi/lo split)
__global__ __launch_bounds__(256) void cast_w(const float* __restrict__ w,
                                              u16* __restrict__ whi,
                                              u16* __restrict__ wlo) {
    int i = blockIdx.x * 256 + threadIdx.x;
    if (i >= COUT_ * 2 * C_) return;
    float v = w[i];
    u16 h = f2bf(v);
    whi[i] = h;
    wlo[i] = f2bf(v - bf2f(h));
}

// K1c: global max of norm2 (single block)
__global__ __launch_bounds__(256) void norm_max(const float* __restrict__ norm2,
                                                int* __restrict__ maxbits) {
    const int tid = threadIdx.x;
    float m = 0.0f;
    for (int i = tid; i < NTOK_; i += 256) m = fmaxf(m, norm2[i]);
#pragma unroll
    for (int d = 1; d < 64; d <<= 1) m = fmaxf(m, __shfl_xor(m, d));
    __shared__ float wmax[4];
    if ((tid & 63) == 0) wmax[tid >> 6] = m;
    __syncthreads();
    if (tid == 0) {
        float mm = fmaxf(fmaxf(wmax[0], wmax[1]), fmaxf(wmax[2], wmax[3]));
        *maxbits = __float_as_int(mm);
    }
}

// ---------------------------------------------------------------------------
// K2: MFMA flash attention, transposed-S, 4-way split-K.
// R11: exact R8 staging/structure (R9/R10 register-prefetch caused scratch
// spills -> 3x HBM traffic; reverted). New: S accumulated in TWO independent
// MFMA chains (Sa: even kc, Sb: odd kc) to halve the 18-deep dependent-MFMA
// latency chain; dual l accumulators likewise.
__global__ __launch_bounds__(256, 3) void flash_attn_mfma32(const u16* __restrict__ xt_hi,
                                                            const u16* __restrict__ xt_lo,
                                                            const u16* __restrict__ xc_hi,
                                                            const float* __restrict__ norm2,
                                                            const int* __restrict__ maxbits,
                                                            float* __restrict__ attT,
                                                            float* __restrict__ l_arr) {
    __shared__ u16 Kh[64 * QROW];
    __shared__ u16 Kl[64 * QROW];
    __shared__ u16 VT[96 * VROW];
    const int b     = blockIdx.y;
    const int i0    = blockIdx.x * 128;
    const int split = blockIdx.z;
    const int kt0   = (49 * split) / NSPLIT;
    const int kt1   = (49 * (split + 1)) / NSPLIT;
    const int tid   = threadIdx.x;
    const int lane  = tid & 63;
    const int w     = tid >> 6;
    const int col   = lane & 31;
    const int g     = lane >> 5;

    const u16* th = xt_hi + (size_t)b * N_ * C_;
    const u16* tl = xt_lo + (size_t)b * N_ * C_;
    const u16* vh = xc_hi + (size_t)b * C_ * N_;

    // Q B-frags from global, once (lane holds its own q-row)
    const int qrow  = i0 + w * 32 + col;
    const int qrowc = qrow < N_ ? qrow : N_ - 1;
    short8 qh[6], ql[6];
#pragma unroll
    for (int kc = 0; kc < 6; kc++) {
        qh[kc] = *(const short8*)&th[(size_t)qrowc * C_ + kc * 16 + g * 8];
        ql[kc] = *(const short8*)&tl[(size_t)qrowc * C_ + kc * 16 + g * 8];
    }
    const float maxn2 = __int_as_float(*maxbits);
    const float m_i   = sqrtf(norm2[(size_t)b * N_ + qrowc] * maxn2);
    float l0 = 0.0f, l1 = 0.0f;
    f32x16 O0 = {0}, O1 = {0}, O2 = {0};

    for (int kt = kt0; kt < kt1; kt++) {
        const int n0 = kt * 64;
        __syncthreads();   // prior tile's frag reads done
        for (int e = tid; e < 1536; e += 256) {       // K: 64 rows x 24 ushort4
            int r = e / 24, c = (e % 24) * 4;
            *(ushort4*)&Kh[r * QROW + c] = *(const ushort4*)&th[(size_t)(n0 + r) * C_ + c];
            *(ushort4*)&Kl[r * QROW + c] = *(const ushort4*)&tl[(size_t)(n0 + r) * C_ + c];
        }
        for (int e = tid; e < 1536; e += 256) {       // V^T: 96 ch x 16 ushort4
            int r = e / 16, j = (e % 16) * 4;
            *(ushort4*)&VT[r * VROW + j] = *(const ushort4*)&vh[(size_t)r * N_ + n0 + j];
        }
        __syncthreads();

        u32 w8[2][8];
#pragma unroll
        for (int jt = 0; jt < 2; jt++) {
            f32x16 Sa = {0}, Sb = {0};
#pragma unroll
            for (int kc = 0; kc < 6; kc++) {
                short8 kh = *(const short8*)&Kh[(jt * 32 + col) * QROW + kc * 16 + g * 8];
                short8 kl = *(const short8*)&Kl[(jt * 32 + col) * QROW + kc * 16 + g * 8];
                if (kc & 1) {
                    Sb = __builtin_amdgcn_mfma_f32_32x32x16_bf16(kh, ql[kc], Sb, 0, 0, 0);
                    Sb = __builtin_amdgcn_mfma_f32_32x32x16_bf16(kl, qh[kc], Sb, 0, 0, 0);
                    Sb = __builtin_amdgcn_mfma_f32_32x32x16_bf16(kh, qh[kc], Sb, 0, 0, 0);
                } else {
                    Sa = __builtin_amdgcn_mfma_f32_32x32x16_bf16(kh, ql[kc], Sa, 0, 0, 0);
                    Sa = __builtin_amdgcn_mfma_f32_32x32x16_bf16(kl, qh[kc], Sa, 0, 0, 0);
                    Sa = __builtin_amdgcn_mfma_f32_32x32x16_bf16(kh, qh[kc], Sa, 0, 0, 0);
                }
            }
            float p[16];
#pragma unroll
            for (int r = 0; r < 16; r++) {
                p[r] = __expf(Sa[r] + Sb[r] - m_i);
                if (jt) l1 += p[r]; else l0 += p[r];
            }
#pragma unroll
            for (int q = 0; q < 8; q++) w8[jt][q] = packbf2(p[2 * q], p[2 * q + 1]);
        }

#pragma unroll
        for (int kc = 0; kc < 4; kc++) {
            const int jt = kc >> 1, qb = (kc & 1) * 4;
            u32 a0 = w8[jt][qb + 0], a1 = w8[jt][qb + 1];
            u32 a2 = w8[jt][qb + 2], a3 = w8[jt][qb + 3];
            u32 s0 = __shfl_xor((int)a0, 32), s1 = __shfl_xor((int)a1, 32);
            u32 s2 = __shfl_xor((int)a2, 32), s3 = __shfl_xor((int)a3, 32);
            union { short8 v; u32 u[4]; } Bf;
            Bf.u[0] = g ? s2 : a0;
            Bf.u[1] = g ? s3 : a1;
            Bf.u[2] = g ? a2 : s0;
            Bf.u[3] = g ? a3 : s1;
            short8 v0 = *(const short8*)&VT[(col)      * VROW + kc * 16 + g * 8];
            short8 v1 = *(const short8*)&VT[(32 + col) * VROW + kc * 16 + g * 8];
            short8 v2 = *(const short8*)&VT[(64 + col) * VROW + kc * 16 + g * 8];
            O0 = __builtin_amdgcn_mfma_f32_32x32x16_bf16(v0, Bf.v, O0, 0, 0, 0);
            O1 = __builtin_amdgcn_mfma_f32_32x32x16_bf16(v1, Bf.v, O1, 0, 0, 0);
            O2 = __builtin_amdgcn_mfma_f32_32x32x16_bf16(v2, Bf.v, O2, 0, 0, 0);
        }
    }

    if (qrow < N_) {
        float* ab = attT + (size_t)b * C_ * N_ + qrow;
#pragma unroll
        for (int r = 0; r < 16; r++) {
            int c = (r & 3) + 8 * (r >> 2) + 4 * g;
            atomicAdd(&ab[(size_t)(c)      * N_], O0[r]);
            atomicAdd(&ab[(size_t)(c + 32) * N_], O1[r]);
            atomicAdd(&ab[(size_t)(c + 64) * N_], O2[r]);
        }
        float l_acc = l0 + l1;
        float l_tot = l_acc + __shfl_xor(l_acc, 32);
        if (g == 0) atomicAdd(&l_arr[(size_t)b * N_ + qrow], l_tot);
    }
}

// ---------------------------------------------------------------------------
// K3: MFMA 1x1 conv (unchanged — HW-verified)
__global__ __launch_bounds__(256, 3) void conv_mfma(const float* __restrict__ x,
                                                    const float* __restrict__ attT,
                                                    const float* __restrict__ l_arr,
                                                    const u16* __restrict__ whi,
                                                    const u16* __restrict__ wlo,
                                                    const float* __restrict__ convb,
                                                    float* __restrict__ y) {
    __shared__ u16 ch[64 * CROW];
    __shared__ u16 cl[64 * CROW];
    __shared__ float invl[64];
    const int b   = blockIdx.x / (N_ / 64);
    const int n0  = (blockIdx.x % (N_ / 64)) * 64;
    const int tid = threadIdx.x;

    if (tid < 64) invl[tid] = 1.0f / l_arr[(size_t)b * N_ + n0 + tid];
    __syncthreads();

    const float* xb = x    + (size_t)b * C_ * N_ + n0;
    const float* ab = attT + (size_t)b * C_ * N_ + n0;
    for (int e = tid; e < 64 * C_; e += 256) {
        int c = e >> 6, t = e & 63;
        float xv = xb[(size_t)c * N_ + t];
        float au = ab[(size_t)c * N_ + t];
        float xj = fmaxf(xv - au * invl[t], 0.0f);
        u16 h1 = f2bf(xv);
        ch[t * CROW + c] = h1;
        cl[t * CROW + c] = f2bf(xv - bf2f(h1));
        u16 h2 = f2bf(xj);
        ch[t * CROW + C_ + c] = h2;
        cl[t * CROW + C_ + c] = f2bf(xj - bf2f(h2));
    }
    __syncthreads();

    const int lane = tid & 63;
    const int w    = tid >> 6;
    const int col  = lane & 31;
    const int g    = lane >> 5;
    const int nt   = w & 1;
    const int m0   = (w >> 1) * 3;

    f32x16 A[3] = {{0}, {0}, {0}};
#pragma unroll
    for (int ks = 0; ks < 12; ks++) {
        const int k0 = ks * 16;
        short8 bh = *(const short8*)&ch[(nt * 32 + col) * CROW + k0 + g * 8];
        short8 bl = *(const short8*)&cl[(nt * 32 + col) * CROW + k0 + g * 8];
#pragma unroll
        for (int mt = 0; mt < 3; mt++) {
            const size_t wo = (size_t)((m0 + mt) * 32 + col) * (2 * C_) + k0 + g * 8;
            short8 ah = *(const short8*)&whi[wo];
            short8 al = *(const short8*)&wlo[wo];
            A[mt] = __builtin_amdgcn_mfma_f32_32x32x16_bf16(ah, bl, A[mt], 0, 0, 0);
            A[mt] = __builtin_amdgcn_mfma_f32_32x32x16_bf16(al, bh, A[mt], 0, 0, 0);
            A[mt] = __builtin_amdgcn_mfma_f32_32x32x16_bf16(ah, bh, A[mt], 0, 0, 0);
        }
    }

    float* yb = y + (size_t)b * COUT_ * N_ + n0 + nt * 32 + col;
#pragma unroll
    for (int mt = 0; mt < 3; mt++)
#pragma unroll
        for (int r = 0; r < 16; r++) {
            int o = (m0 + mt) * 32 + (r & 3) + 8 * (r >> 2) + 4 * g;
            yb[(size_t)o * N_] = A[mt][r] + convb[o];
        }
}

// ---------------------------------------------------------------------------
// K4: per-channel BN stats from y -> scale/shift (one block per channel)
__global__ __launch_bounds__(256) void bn_stats(const float* __restrict__ y,
                                                const float* __restrict__ gamma,
                                                const float* __restrict__ beta,
                                                float* __restrict__ ss) {
    const int o   = blockIdx.x;
    const int tid = threadIdx.x;
    float s = 0.0f, q = 0.0f;
#pragma unroll
    for (int b = 0; b < B_; b++) {
        const float4* p = (const float4*)(y + (size_t)(b * COUT_ + o) * N_);
        for (int i = tid; i < N_ / 4; i += 256) {
            float4 v = p[i];
            s += v.x + v.y + v.z + v.w;
            q += v.x * v.x + v.y * v.y + v.z * v.z + v.w * v.w;
        }
    }
#pragma unroll
    for (int d = 1; d < 64; d <<= 1) {
        s += __shfl_xor(s, d);
        q += __shfl_xor(q, d);
    }
    __shared__ float wss[4], wqq[4];
    if ((tid & 63) == 0) { wss[tid >> 6] = s; wqq[tid >> 6] = q; }
    __syncthreads();
    if (tid == 0) {
        float st = wss[0] + wss[1] + wss[2] + wss[3];
        float qt = wqq[0] + wqq[1] + wqq[2] + wqq[3];
        const float invn = 1.0f / (float)NTOK_;
        float mean = st * invn;
        float var  = qt * invn - mean * mean;
        float sc   = gamma[o] * rsqrtf(var + BN_EPS);
        ss[o]         = sc;
        ss[COUT_ + o] = beta[o] - mean * sc;
    }
}

// K5: y -> BN affine -> exact GELU -> fp32 out
__global__ __launch_bounds__(256) void bn_gelu_out(const float* __restrict__ y,
                                                   const float* __restrict__ ss,
                                                   float* __restrict__ out) {
    const int total4 = (B_ * COUT_ * N_) / 4;
    int i = blockIdx.x * 256 + threadIdx.x;
    if (i >= total4) return;
    int base = i * 4;
    int o = (base / N_) % COUT_;
    float sc = ss[o], sh = ss[COUT_ + o];
    float4 v = *(const float4*)&y[base];
    float u0 = fmaf(v.x, sc, sh), u1 = fmaf(v.y, sc, sh);
    float u2 = fmaf(v.z, sc, sh), u3 = fmaf(v.w, sc, sh);
    const float k = 0.70710678118654752f;
    float4 g;
    g.x = 0.5f * u0 * (1.0f + erff(u0 * k));
    g.y = 0.5f * u1 * (1.0f + erff(u1 * k));
    g.z = 0.5f * u2 * (1.0f + erff(u2 * k));
    g.w = 0.5f * u3 * (1.0f + erff(u3 * k));
    *(float4*)&out[base] = g;
}

// ---------------------------------------------------------------------------
extern "C" void kernel_launch(void* const* d_in, const int* in_sizes, int n_in,
                              void* d_out, int out_size, void* d_ws, size_t ws_size,
                              hipStream_t stream) {
    const float* x     = (const float*)d_in[0];
    const float* w     = (const float*)d_in[1];
    const float* cb    = (const float*)d_in[2];
    const float* gamma = (const float*)d_in[3];
    const float* beta  = (const float*)d_in[4];

    u16* xt_hi = (u16*)d_ws;                         // BNC bf16
    u16* xt_lo = xt_hi + (size_t)BNC;                // BNC
    u16* xc_hi = xt_lo + (size_t)BNC;                // BNC
    float* attT  = (float*)(xc_hi + (size_t)BNC);    // BNC fp32 (channel-major, unnormalized)
    u16* whi   = (u16*)(attT + (size_t)BNC);         // 192*192 bf16
    u16* wlo   = whi + COUT_ * 2 * C_;               // 192*192 bf16
    float* y     = (float*)(wlo + COUT_ * 2 * C_);   // B*COUT*N fp32
    float* ss    = y + (size_t)B_ * COUT_ * N_;      // 2*COUT
    float* l_arr = ss + 2 * COUT_;                   // NTOK
    float* norm2 = l_arr + NTOK_;                    // NTOK
    int*   maxb  = (int*)(norm2 + NTOK_);            // 1

    hipMemsetAsync(l_arr, 0, NTOK_ * sizeof(float), stream);
    hipMemsetAsync(norm2, 0, NTOK_ * sizeof(float), stream);
    hipMemsetAsync(attT, 0, (size_t)BNC * sizeof(float), stream);

    transpose_split<<<dim3(N_ / 32, C_ / 32, B_), 256, 0, stream>>>(x, xt_hi, xt_lo, xc_hi, norm2);
    cast_w<<<dim3((COUT_ * 2 * C_ + 255) / 256), 256, 0, stream>>>(w, whi, wlo);
    norm_max<<<dim3(1), 256, 0, stream>>>(norm2, maxb);
    flash_attn_mfma32<<<dim3((N_ + 127) / 128, B_, NSPLIT), 256, 0, stream>>>(
        xt_hi, xt_lo, xc_hi, norm2, maxb, attT, l_arr);
    conv_mfma<<<dim3(B_ * (N_ / 64)), 256, 0, stream>>>(x, attT, l_arr, whi, wlo, cb, y);
    bn_stats<<<dim3(COUT_), 256, 0, stream>>>(y, gamma, beta, ss);
    bn_gelu_out<<<dim3((B_ * COUT_ * N_ / 4 + 255) / 256), 256, 0, stream>>>(y, ss, (float*)d_out);
}

// Round 12
// 296.491 us; speedup vs baseline: 1.4450x; 1.4450x over previous
//
#include <hip/hip_runtime.h>
#include <hip/hip_bf16.h>

// Problem constants
#define B_    8
#define C_    96
#define N_    3136      // 56*56
#define COUT_ 192
#define NTOK_ 25088     // B_*N_
#define BN_EPS 1e-5f

#define QROW 104        // K LDS token-row stride in bf16 (96+8), 16B-multiple rows
#define VROW 72         // VT row stride in bf16 (64+8), 16B-multiple
#define CROW 200        // conv cat LDS token-row stride in bf16 (192+8), 16B-multiple
#define BNC  (B_ * N_ * C_)
#define NSPLIT 4

typedef __hip_bfloat16 bf16;
typedef unsigned short u16;
typedef unsigned int u32;
typedef __attribute__((ext_vector_type(8))) short short8;    // 8 bf16 = 16B (MFMA A/B frag)
typedef __attribute__((ext_vector_type(16))) float f32x16;   // 32x32 MFMA C/D frag

__device__ __forceinline__ u16 f2bf(float f) {
    union { __hip_bfloat16 h; u16 u; } cv;
    cv.h = __float2bfloat16(f);
    return cv.u;
}
__device__ __forceinline__ float bf2f(u16 v) {
    union { u16 u; __hip_bfloat16 h; } cv;
    cv.u = v;
    return __bfloat162float(cv.h);
}
__device__ __forceinline__ u32 packbf2(float lo, float hi) {
    return ((u32)f2bf(hi) << 16) | (u32)f2bf(lo);
}

// ---------------------------------------------------------------------------
// K1: x [B][C][N] fp32 -> xt_hi/xt_lo [B][N][C] bf16 (token-major, hi/lo split)
//                         xc_hi [B][C][N] bf16 (channel-major, for V^T staging)
// Fused: per-token squared-norm partial sums (32 channels per block) -> norm2.
__global__ __launch_bounds__(256) void transpose_split(const float* __restrict__ x,
                                                       u16* __restrict__ xt_hi,
                                                       u16* __restrict__ xt_lo,
                                                       u16* __restrict__ xc_hi,
                                                       float* __restrict__ norm2) {
    __shared__ float tile[32][33];
    __shared__ float nrm[32];
    const int nb = blockIdx.x * 32;
    const int cb = blockIdx.y * 32;
    const int b  = blockIdx.z;
    const int tid = threadIdx.x;
    const int tx = tid & 31;
    const int ty = tid >> 5;
    if (tid < 32) nrm[tid] = 0.0f;
    float psum = 0.0f;
#pragma unroll
    for (int r = 0; r < 32; r += 8) {
        size_t idx = ((size_t)b * C_ + cb + ty + r) * N_ + nb + tx;
        float v = x[idx];
        tile[ty + r][tx] = v;
        xc_hi[idx] = f2bf(v);
        psum = fmaf(v, v, psum);
    }
    __syncthreads();               // tile visible; nrm init done
    atomicAdd(&nrm[tx], psum);     // LDS atomic, 8 adders per slot
#pragma unroll
    for (int r = 0; r < 32; r += 8) {
        float v = tile[tx][ty + r];
        u16 h = f2bf(v);
        size_t o = ((size_t)b * N_ + nb + ty + r) * C_ + cb + tx;
        xt_hi[o] = h;
        xt_lo[o] = f2bf(v - bf2f(h));
    }
    __syncthreads();               // nrm complete
    if (tid < 32)
        atomicAdd(&norm2[(size_t)b * N_ + nb + tid], nrm[tid]);
}

// K1b: conv_w [O][2C] fp32 -> whi/wlo bf16 (same [o][c] layout, hi/lo split)
__global__ __launch_bounds__(256) void cast_w(const float* __restrict__ w,
                                              u16* __restrict__ whi,
                                              u16* __restrict__ wlo) {
    int i = blockIdx.x * 256 + threadIdx.x;
    if (i >= COUT_ * 2 * C_) return;
    float v = w[i];
    u16 h = f2bf(v);
    whi[i] = h;
    wlo[i] = f2bf(v - bf2f(h));
}

// K1c: global max of norm2 (single block)
__global__ __launch_bounds__(256) void norm_max(const float* __restrict__ norm2,
                                                int* __restrict__ maxbits) {
    const int tid = threadIdx.x;
    float m = 0.0f;
    for (int i = tid; i < NTOK_; i += 256) m = fmaxf(m, norm2[i]);
#pragma unroll
    for (int d = 1; d < 64; d <<= 1) m = fmaxf(m, __shfl_xor(m, d));
    __shared__ float wmax[4];
    if ((tid & 63) == 0) wmax[tid >> 6] = m;
    __syncthreads();
    if (tid == 0) {
        float mm = fmaxf(fmaxf(wmax[0], wmax[1]), fmaxf(wmax[2], wmax[3]));
        *maxbits = __float_as_int(mm);
    }
}

// ---------------------------------------------------------------------------
// K2: MFMA flash attention, transposed-S, 4-way split-K.
// R12: EXACT R8 body restored. R9 (reg prefetch), R10 (same), R11 (dual S
// chains) all spilled to scratch — the kernel sits at the unified VGPR/AGPR
// cliff; spill signature = FETCH/WRITE inflation at constant VGPR_Count.
// Do NOT add registers to this kernel.
__global__ __launch_bounds__(256, 3) void flash_attn_mfma32(const u16* __restrict__ xt_hi,
                                                            const u16* __restrict__ xt_lo,
                                                            const u16* __restrict__ xc_hi,
                                                            const float* __restrict__ norm2,
                                                            const int* __restrict__ maxbits,
                                                            float* __restrict__ attT,
                                                            float* __restrict__ l_arr) {
    __shared__ u16 Kh[64 * QROW];
    __shared__ u16 Kl[64 * QROW];
    __shared__ u16 VT[96 * VROW];
    const int b     = blockIdx.y;
    const int i0    = blockIdx.x * 128;
    const int split = blockIdx.z;
    const int kt0   = (49 * split) / NSPLIT;
    const int kt1   = (49 * (split + 1)) / NSPLIT;
    const int tid   = threadIdx.x;
    const int lane  = tid & 63;
    const int w     = tid >> 6;
    const int col   = lane & 31;
    const int g     = lane >> 5;

    const u16* th = xt_hi + (size_t)b * N_ * C_;
    const u16* tl = xt_lo + (size_t)b * N_ * C_;
    const u16* vh = xc_hi + (size_t)b * C_ * N_;

    // Q B-frags from global, once (lane holds its own q-row)
    const int qrow  = i0 + w * 32 + col;
    const int qrowc = qrow < N_ ? qrow : N_ - 1;
    short8 qh[6], ql[6];
#pragma unroll
    for (int kc = 0; kc < 6; kc++) {
        qh[kc] = *(const short8*)&th[(size_t)qrowc * C_ + kc * 16 + g * 8];
        ql[kc] = *(const short8*)&tl[(size_t)qrowc * C_ + kc * 16 + g * 8];
    }
    const float maxn2 = __int_as_float(*maxbits);
    const float m_i   = sqrtf(norm2[(size_t)b * N_ + qrowc] * maxn2);
    float l_acc = 0.0f;
    f32x16 O0 = {0}, O1 = {0}, O2 = {0};

    for (int kt = kt0; kt < kt1; kt++) {
        const int n0 = kt * 64;
        __syncthreads();   // prior tile's frag reads done
        for (int e = tid; e < 1536; e += 256) {       // K: 64 rows x 24 ushort4
            int r = e / 24, c = (e % 24) * 4;
            *(ushort4*)&Kh[r * QROW + c] = *(const ushort4*)&th[(size_t)(n0 + r) * C_ + c];
            *(ushort4*)&Kl[r * QROW + c] = *(const ushort4*)&tl[(size_t)(n0 + r) * C_ + c];
        }
        for (int e = tid; e < 1536; e += 256) {       // V^T: 96 ch x 16 ushort4
            int r = e / 16, j = (e % 16) * 4;
            *(ushort4*)&VT[r * VROW + j] = *(const ushort4*)&vh[(size_t)r * N_ + n0 + j];
        }
        __syncthreads();

        u32 w8[2][8];
#pragma unroll
        for (int jt = 0; jt < 2; jt++) {
            f32x16 S = {0};
#pragma unroll
            for (int kc = 0; kc < 6; kc++) {
                short8 kh = *(const short8*)&Kh[(jt * 32 + col) * QROW + kc * 16 + g * 8];
                short8 kl = *(const short8*)&Kl[(jt * 32 + col) * QROW + kc * 16 + g * 8];
                S = __builtin_amdgcn_mfma_f32_32x32x16_bf16(kh, ql[kc], S, 0, 0, 0);
                S = __builtin_amdgcn_mfma_f32_32x32x16_bf16(kl, qh[kc], S, 0, 0, 0);
                S = __builtin_amdgcn_mfma_f32_32x32x16_bf16(kh, qh[kc], S, 0, 0, 0);
            }
            float p[16];
#pragma unroll
            for (int r = 0; r < 16; r++) {
                p[r] = __expf(S[r] - m_i);
                l_acc += p[r];
            }
#pragma unroll
            for (int q = 0; q < 8; q++) w8[jt][q] = packbf2(p[2 * q], p[2 * q + 1]);
        }

#pragma unroll
        for (int kc = 0; kc < 4; kc++) {
            const int jt = kc >> 1, qb = (kc & 1) * 4;
            u32 a0 = w8[jt][qb + 0], a1 = w8[jt][qb + 1];
            u32 a2 = w8[jt][qb + 2], a3 = w8[jt][qb + 3];
            u32 s0 = __shfl_xor((int)a0, 32), s1 = __shfl_xor((int)a1, 32);
            u32 s2 = __shfl_xor((int)a2, 32), s3 = __shfl_xor((int)a3, 32);
            union { short8 v; u32 u[4]; } Bf;
            Bf.u[0] = g ? s2 : a0;
            Bf.u[1] = g ? s3 : a1;
            Bf.u[2] = g ? a2 : s0;
            Bf.u[3] = g ? a3 : s1;
            short8 v0 = *(const short8*)&VT[(col)      * VROW + kc * 16 + g * 8];
            short8 v1 = *(const short8*)&VT[(32 + col) * VROW + kc * 16 + g * 8];
            short8 v2 = *(const short8*)&VT[(64 + col) * VROW + kc * 16 + g * 8];
            O0 = __builtin_amdgcn_mfma_f32_32x32x16_bf16(v0, Bf.v, O0, 0, 0, 0);
            O1 = __builtin_amdgcn_mfma_f32_32x32x16_bf16(v1, Bf.v, O1, 0, 0, 0);
            O2 = __builtin_amdgcn_mfma_f32_32x32x16_bf16(v2, Bf.v, O2, 0, 0, 0);
        }
    }

    if (qrow < N_) {
        float* ab = attT + (size_t)b * C_ * N_ + qrow;
#pragma unroll
        for (int r = 0; r < 16; r++) {
            int c = (r & 3) + 8 * (r >> 2) + 4 * g;
            atomicAdd(&ab[(size_t)(c)      * N_], O0[r]);
            atomicAdd(&ab[(size_t)(c + 32) * N_], O1[r]);
            atomicAdd(&ab[(size_t)(c + 64) * N_], O2[r]);
        }
        float l_tot = l_acc + __shfl_xor(l_acc, 32);
        if (g == 0) atomicAdd(&l_arr[(size_t)b * N_ + qrow], l_tot);
    }
}

// ---------------------------------------------------------------------------
// K3: MFMA 1x1 conv (unchanged — HW-verified)
__global__ __launch_bounds__(256, 3) void conv_mfma(const float* __restrict__ x,
                                                    const float* __restrict__ attT,
                                                    const float* __restrict__ l_arr,
                                                    const u16* __restrict__ whi,
                                                    const u16* __restrict__ wlo,
                                                    const float* __restrict__ convb,
                                                    float* __restrict__ y) {
    __shared__ u16 ch[64 * CROW];
    __shared__ u16 cl[64 * CROW];
    __shared__ float invl[64];
    const int b   = blockIdx.x / (N_ / 64);
    const int n0  = (blockIdx.x % (N_ / 64)) * 64;
    const int tid = threadIdx.x;

    if (tid < 64) invl[tid] = 1.0f / l_arr[(size_t)b * N_ + n0 + tid];
    __syncthreads();

    const float* xb = x    + (size_t)b * C_ * N_ + n0;
    const float* ab = attT + (size_t)b * C_ * N_ + n0;
    for (int e = tid; e < 64 * C_; e += 256) {
        int c = e >> 6, t = e & 63;
        float xv = xb[(size_t)c * N_ + t];
        float au = ab[(size_t)c * N_ + t];
        float xj = fmaxf(xv - au * invl[t], 0.0f);
        u16 h1 = f2bf(xv);
        ch[t * CROW + c] = h1;
        cl[t * CROW + c] = f2bf(xv - bf2f(h1));
        u16 h2 = f2bf(xj);
        ch[t * CROW + C_ + c] = h2;
        cl[t * CROW + C_ + c] = f2bf(xj - bf2f(h2));
    }
    __syncthreads();

    const int lane = tid & 63;
    const int w    = tid >> 6;
    const int col  = lane & 31;
    const int g    = lane >> 5;
    const int nt   = w & 1;
    const int m0   = (w >> 1) * 3;

    f32x16 A[3] = {{0}, {0}, {0}};
#pragma unroll
    for (int ks = 0; ks < 12; ks++) {
        const int k0 = ks * 16;
        short8 bh = *(const short8*)&ch[(nt * 32 + col) * CROW + k0 + g * 8];
        short8 bl = *(const short8*)&cl[(nt * 32 + col) * CROW + k0 + g * 8];
#pragma unroll
        for (int mt = 0; mt < 3; mt++) {
            const size_t wo = (size_t)((m0 + mt) * 32 + col) * (2 * C_) + k0 + g * 8;
            short8 ah = *(const short8*)&whi[wo];
            short8 al = *(const short8*)&wlo[wo];
            A[mt] = __builtin_amdgcn_mfma_f32_32x32x16_bf16(ah, bl, A[mt], 0, 0, 0);
            A[mt] = __builtin_amdgcn_mfma_f32_32x32x16_bf16(al, bh, A[mt], 0, 0, 0);
            A[mt] = __builtin_amdgcn_mfma_f32_32x32x16_bf16(ah, bh, A[mt], 0, 0, 0);
        }
    }

    float* yb = y + (size_t)b * COUT_ * N_ + n0 + nt * 32 + col;
#pragma unroll
    for (int mt = 0; mt < 3; mt++)
#pragma unroll
        for (int r = 0; r < 16; r++) {
            int o = (m0 + mt) * 32 + (r & 3) + 8 * (r >> 2) + 4 * g;
            yb[(size_t)o * N_] = A[mt][r] + convb[o];
        }
}

// ---------------------------------------------------------------------------
// K4: per-channel BN stats from y -> scale/shift (one block per channel)
__global__ __launch_bounds__(256) void bn_stats(const float* __restrict__ y,
                                                const float* __restrict__ gamma,
                                                const float* __restrict__ beta,
                                                float* __restrict__ ss) {
    const int o   = blockIdx.x;
    const int tid = threadIdx.x;
    float s = 0.0f, q = 0.0f;
#pragma unroll
    for (int b = 0; b < B_; b++) {
        const float4* p = (const float4*)(y + (size_t)(b * COUT_ + o) * N_);
        for (int i = tid; i < N_ / 4; i += 256) {
            float4 v = p[i];
            s += v.x + v.y + v.z + v.w;
            q += v.x * v.x + v.y * v.y + v.z * v.z + v.w * v.w;
        }
    }
#pragma unroll
    for (int d = 1; d < 64; d <<= 1) {
        s += __shfl_xor(s, d);
        q += __shfl_xor(q, d);
    }
    __shared__ float wss[4], wqq[4];
    if ((tid & 63) == 0) { wss[tid >> 6] = s; wqq[tid >> 6] = q; }
    __syncthreads();
    if (tid == 0) {
        float st = wss[0] + wss[1] + wss[2] + wss[3];
        float qt = wqq[0] + wqq[1] + wqq[2] + wqq[3];
        const float invn = 1.0f / (float)NTOK_;
        float mean = st * invn;
        float var  = qt * invn - mean * mean;
        float sc   = gamma[o] * rsqrtf(var + BN_EPS);
        ss[o]         = sc;
        ss[COUT_ + o] = beta[o] - mean * sc;
    }
}

// K5: y -> BN affine -> exact GELU -> fp32 out
__global__ __launch_bounds__(256) void bn_gelu_out(const float* __restrict__ y,
                                                   const float* __restrict__ ss,
                                                   float* __restrict__ out) {
    const int total4 = (B_ * COUT_ * N_) / 4;
    int i = blockIdx.x * 256 + threadIdx.x;
    if (i >= total4) return;
    int base = i * 4;
    int o = (base / N_) % COUT_;
    float sc = ss[o], sh = ss[COUT_ + o];
    float4 v = *(const float4*)&y[base];
    float u0 = fmaf(v.x, sc, sh), u1 = fmaf(v.y, sc, sh);
    float u2 = fmaf(v.z, sc, sh), u3 = fmaf(v.w, sc, sh);
    const float k = 0.70710678118654752f;
    float4 g;
    g.x = 0.5f * u0 * (1.0f + erff(u0 * k));
    g.y = 0.5f * u1 * (1.0f + erff(u1 * k));
    g.z = 0.5f * u2 * (1.0f + erff(u2 * k));
    g.w = 0.5f * u3 * (1.0f + erff(u3 * k));
    *(float4*)&out[base] = g;
}

// ---------------------------------------------------------------------------
extern "C" void kernel_launch(void* const* d_in, const int* in_sizes, int n_in,
                              void* d_out, int out_size, void* d_ws, size_t ws_size,
                              hipStream_t stream) {
    const float* x     = (const float*)d_in[0];
    const float* w     = (const float*)d_in[1];
    const float* cb    = (const float*)d_in[2];
    const float* gamma = (const float*)d_in[3];
    const float* beta  = (const float*)d_in[4];

    u16* xt_hi = (u16*)d_ws;                         // BNC bf16
    u16* xt_lo = xt_hi + (size_t)BNC;                // BNC
    u16* xc_hi = xt_lo + (size_t)BNC;                // BNC
    float* attT  = (float*)(xc_hi + (size_t)BNC);    // BNC fp32 (channel-major, unnormalized)
    u16* whi   = (u16*)(attT + (size_t)BNC);         // 192*192 bf16
    u16* wlo   = whi + COUT_ * 2 * C_;               // 192*192 bf16
    float* y     = (float*)(wlo + COUT_ * 2 * C_);   // B*COUT*N fp32
    float* ss    = y + (size_t)B_ * COUT_ * N_;      // 2*COUT
    float* l_arr = ss + 2 * COUT_;                   // NTOK
    float* norm2 = l_arr + NTOK_;                    // NTOK
    int*   maxb  = (int*)(norm2 + NTOK_);            // 1

    hipMemsetAsync(l_arr, 0, NTOK_ * sizeof(float), stream);
    hipMemsetAsync(norm2, 0, NTOK_ * sizeof(float), stream);
    hipMemsetAsync(attT, 0, (size_t)BNC * sizeof(float), stream);

    transpose_split<<<dim3(N_ / 32, C_ / 32, B_), 256, 0, stream>>>(x, xt_hi, xt_lo, xc_hi, norm2);
    cast_w<<<dim3((COUT_ * 2 * C_ + 255) / 256), 256, 0, stream>>>(w, whi, wlo);
    norm_max<<<dim3(1), 256, 0, stream>>>(norm2, maxb);
    flash_attn_mfma32<<<dim3((N_ + 127) / 128, B_, NSPLIT), 256, 0, stream>>>(
        xt_hi, xt_lo, xc_hi, norm2, maxb, attT, l_arr);
    conv_mfma<<<dim3(B_ * (N_ / 64)), 256, 0, stream>>>(x, attT, l_arr, whi, wlo, cb, y);
    bn_stats<<<dim3(COUT_), 256, 0, stream>>>(y, gamma, beta, ss);
    bn_gelu_out<<<dim3((B_ * COUT_ * N_ / 4 + 255) / 256), 256, 0, stream>>>(y, ss, (float*)d_out);
}